// Round 1
// baseline (2893.349 us; speedup 1.0000x reference)
//
#include <hip/hip_runtime.h>
#include <hip/hip_bf16.h>

#define NSTEPS 100
#define DT (1.0f / 100.0f)
#define TSCALE 2.885390081777927f   // 2*log2(e): folded into W1,W2,b1,b2

typedef __attribute__((ext_vector_type(8))) short short8;   // 8 bf16 (MFMA A/B frag)
typedef __attribute__((ext_vector_type(4))) float floatx4;  // MFMA C/D frag

__device__ __forceinline__ unsigned short f2bf(float f) {
  union { float f; unsigned int u; } v; v.f = f;
  unsigned int u = v.u;
  return (unsigned short)((u + 0x7fffu + ((u >> 16) & 1u)) >> 16);  // RNE
}
__device__ __forceinline__ unsigned int pk2(float a, float b) {
  __hip_bfloat162 h = __float22bfloat162_rn(make_float2(a, b));
  union { __hip_bfloat162 h; unsigned int u; } v; v.h = h;
  return v.u;
}
// tanh with input pre-scaled by 2*log2(e): tanh = 1 - 2/(2^y + 1)
__device__ __forceinline__ float tanh_pre(float y) {
  float e = __builtin_amdgcn_exp2f(y);
  return 1.0f - 2.0f * __builtin_amdgcn_rcpf(e + 1.0f);
}

// Repack W (K x N row-major fp32) into frag-major bf16 (A-frag of W^T).
// W1/W2 are pre-scaled by TSCALE (tanh input scale folded in).
__global__ void prep_weights(const float* __restrict__ W1,
                             const float* __restrict__ W2,
                             const float* __restrict__ W3,
                             unsigned short* __restrict__ ws) {
  int e = blockIdx.x * 256 + threadIdx.x;  // 98304 total
  const float* src; int N, ntile, el, base; float sc;
  if (e < 16384)      { src = W1; N = 256; ntile = 16; base = 0;     el = e;         sc = TSCALE; }
  else if (e < 81920) { src = W2; N = 256; ntile = 16; base = 16384; el = e - 16384; sc = TSCALE; }
  else                { src = W3; N = 64;  ntile = 4;  base = 81920; el = e - 81920; sc = 1.0f; }
  int j = el & 7;
  int l = (el >> 3) & 63;
  int rem = el >> 9;
  int t = rem % ntile;
  int s = rem / ntile;
  int k = s * 32 + ((l >> 4) << 3) + j;
  int n = t * 16 + (l & 15);
  ws[base + el] = f2bf(src[k * N + n] * sc);
}

// Dual-group pipeline (R7 dataflow/barriers) with MFMA and tanh streams
// fused at statement granularity: every unrolled step issues one group's
// MFMAs immediately followed by the other group's tanh+pack, so each
// wave's in-order stream co-fills the matrix and vector pipes.
// W2 register-resident; W1/W3 in LDS frag-major (b128, immediate offsets).
__global__ __launch_bounds__(512, 2)
void cnf_kernel(const float* __restrict__ z0,
                const float* __restrict__ b1,
                const float* __restrict__ b2,
                const float* __restrict__ b3,
                const unsigned short* __restrict__ wsAll,
                float* __restrict__ out) {
  extern __shared__ unsigned short smem[];   // 147456 B
  unsigned short* ZbufA = smem;              //  8192 B (4 nt * 2 s * 512)
  unsigned short* ZbufB = smem + 4096;
  unsigned short* HbufA = smem + 8192;       // 32768 B (4 nt * 8 s * 512)
  unsigned short* HbufB = smem + 24576;
  unsigned short* LW1   = smem + 40960;      // 32768 B (frag-major W1)
  unsigned short* LW3   = smem + 57344;      // 32768 B (frag-major W3)

  const int tid  = threadIdx.x;
  const int wave = tid >> 6;
  const int lane = tid & 63;
  const int i15  = lane & 15;
  const int q    = lane >> 4;
  const int grow = blockIdx.x * 128;         // group A rows; B = +64
  const int mt3  = wave & 3;                 // L3 M-tile
  const int ntp  = wave >> 2;                // L3 N-pair

  const unsigned short* wsW1 = wsAll;
  const unsigned short* wsW2 = wsAll + 16384;
  const unsigned short* wsW3 = wsAll + 81920;

  // ---- W1/W3 -> LDS (once) ----
  {
    const uint4* s1 = (const uint4*)wsW1;
    const uint4* s3 = (const uint4*)wsW3;
    uint4* d1 = (uint4*)LW1;
    uint4* d3 = (uint4*)LW3;
#pragma unroll
    for (int i = 0; i < 4; ++i) { d1[tid + 512 * i] = s1[tid + 512 * i];
                                  d3[tid + 512 * i] = s3[tid + 512 * i]; }
  }

  // ---- register-resident W2 A-frags (64 VGPR) ----
  short8 w2f[8][2];
#pragma unroll
  for (int s = 0; s < 8; ++s)
#pragma unroll
    for (int tt = 0; tt < 2; ++tt)
      w2f[s][tt] = *(const short8*)&wsW2[((s * 16 + 2 * wave + tt) * 64 + lane) * 8];

  // ---- biases as fp32 regs (20); b1/b2 pre-scaled; acc init ----
  float b1a[2][4], b2a[2][4], b3a[4];
#pragma unroll
  for (int tt = 0; tt < 2; ++tt) {
    float4 v1 = *(const float4*)&b1[(2 * wave + tt) * 16 + q * 4];
    float4 v2 = *(const float4*)&b2[(2 * wave + tt) * 16 + q * 4];
    b1a[tt][0] = v1.x * TSCALE; b1a[tt][1] = v1.y * TSCALE;
    b1a[tt][2] = v1.z * TSCALE; b1a[tt][3] = v1.w * TSCALE;
    b2a[tt][0] = v2.x * TSCALE; b2a[tt][1] = v2.y * TSCALE;
    b2a[tt][2] = v2.z * TSCALE; b2a[tt][3] = v2.w * TSCALE;
  }
  *(float4*)b3a = *(const float4*)&b3[mt3 * 16 + q * 4];

  // ---- frag-layout index bases ----
  const int rb  = lane * 8;                                   // act read base; tile adds *512
  const int j0  = 4 * (q & 1);
  const int hw0 = (wave * 64 + i15 + 16 * (q >> 1)) * 8 + j0; // +tt*256, +nt*4096
  const int zw0 = ((mt3 >> 1) * 64 + i15 + 16 * (2 * (mt3 & 1) + (q >> 1))) * 8 + j0;  // +nt*1024
  const int w1b = wave * 1024 + lane * 8;                     // + s*8192 + tt*512
  const int w3b = mt3 * 512 + lane * 8;                       // + s*2048

  // ---- RK4 state, both groups ----
  float zA[8], zaccA[8], zB[8], zaccB[8];
#pragma unroll
  for (int j = 0; j < 2; ++j) {
    const int nt = 2 * ntp + j;
    float4 va = *(const float4*)&z0[(grow + nt * 16 + i15) * 64 + mt3 * 16 + q * 4];
    float4 vb = *(const float4*)&z0[(grow + 64 + nt * 16 + i15) * 64 + mt3 * 16 + q * 4];
    zA[j*4+0]=va.x; zA[j*4+1]=va.y; zA[j*4+2]=va.z; zA[j*4+3]=va.w;
    zB[j*4+0]=vb.x; zB[j*4+1]=vb.y; zB[j*4+2]=vb.z; zB[j*4+3]=vb.w;
#pragma unroll
    for (int r = 0; r < 4; ++r) { zaccA[j*4+r] = 0.f; zaccB[j*4+r] = 0.f; }
    uint2 pa; pa.x = pk2(va.x, va.y); pa.y = pk2(va.z, va.w);
    uint2 pb; pb.x = pk2(vb.x, vb.y); pb.y = pk2(vb.z, vb.w);
    *(uint2*)&ZbufA[zw0 + nt * 1024] = pa;
    *(uint2*)&ZbufB[zw0 + nt * 1024] = pb;
  }

  const float DT6 = DT / 6.0f, DT3 = DT / 3.0f, DTH = 0.5f * DT;

  floatx4 accA[2][4], accB[2][4];

  // ---- helpers ----
  auto initAcc = [&](floatx4 (&a)[2][4], float (&b)[2][4]) {
#pragma unroll
    for (int tt = 0; tt < 2; ++tt)
#pragma unroll
      for (int nt = 0; nt < 4; ++nt)
        a[tt][nt] = floatx4{b[tt][0], b[tt][1], b[tt][2], b[tt][3]};
  };
  // one-eighth of an epilogue: 4 tanh + 2 packs + 1 b64 write
  auto ePart = [&](int u, floatx4 (&a)[2][4], unsigned short* H) {
    const int tt = u >> 2, nt = u & 3;
    uint2 p;
    p.x = pk2(tanh_pre(a[tt][nt][0]), tanh_pre(a[tt][nt][1]));
    p.y = pk2(tanh_pre(a[tt][nt][2]), tanh_pre(a[tt][nt][3]));
    *(uint2*)&H[hw0 + tt * 256 + nt * 4096] = p;
  };
  // one step of L1 (pair u: s=u>>2, nt=u&3): 2 MFMAs
  auto p1Step = [&](int u, const unsigned short* Z, floatx4 (&a)[2][4]) {
    const int s = u >> 2, nt = u & 3;
    short8 wa = *(const short8*)&LW1[w1b + s * 8192];
    short8 wb = *(const short8*)&LW1[w1b + s * 8192 + 512];
    short8 bz = *(const short8*)&Z[rb + (nt * 2 + s) * 512];
    a[0][nt] = __builtin_amdgcn_mfma_f32_16x16x32_bf16(wa, bz, a[0][nt], 0, 0, 0);
    a[1][nt] = __builtin_amdgcn_mfma_f32_16x16x32_bf16(wb, bz, a[1][nt], 0, 0, 0);
  };
  // one s-step of L3: 2 MFMAs
  auto p3Step = [&](int s, const unsigned short* H, floatx4 (&a3)[2]) {
    short8 wf = *(const short8*)&LW3[w3b + s * 2048];
    short8 b0 = *(const short8*)&H[rb + (ntp * 16 + s) * 512];
    short8 b1_ = *(const short8*)&H[rb + (ntp * 16 + 8 + s) * 512];
    a3[0] = __builtin_amdgcn_mfma_f32_16x16x32_bf16(wf, b0, a3[0], 0, 0, 0);
    a3[1] = __builtin_amdgcn_mfma_f32_16x16x32_bf16(wf, b1_, a3[1], 0, 0, 0);
  };
  auto rk4Tail = [&](floatx4 (&a3)[2], float (&z)[8], float (&zacc)[8],
                     unsigned short* Z, int st) {
    const float wsum  = (st == 0 || st == 3) ? DT6 : DT3;
    const float cst   = (st == 2) ? DT : DTH;
    const bool  last  = (st == 3);
    const bool  first = (st == 0);
#pragma unroll
    for (int j = 0; j < 2; ++j) {
      const int nt = 2 * ntp + j;
      float stg[4];
#pragma unroll
      for (int r = 0; r < 4; ++r) {
        const int i = j * 4 + r;
        float k = a3[j][r];
        float za = first ? z[i] : zacc[i];
        za += wsum * k;
        zacc[i] = za;
        if (last) { z[i] = za; stg[r] = za; }
        else      { stg[r] = z[i] + cst * k; }
      }
      uint2 p; p.x = pk2(stg[0], stg[1]); p.y = pk2(stg[2], stg[3]);
      *(uint2*)&Z[zw0 + nt * 1024] = p;
    }
  };

  // ---- prologue: advance B through P1,E1,P2,E2 of stage 0 (unfused) ----
  __syncthreads();                 // Zbuf init + LW1/LW3 visible
  initAcc(accB, b1a);
#pragma unroll
  for (int u = 0; u < 8; ++u) p1Step(u, ZbufB, accB);
#pragma unroll
  for (int u = 0; u < 8; ++u) ePart(u, accB, HbufB);
  __syncthreads();
  initAcc(accB, b2a);
#pragma unroll
  for (int s = 0; s < 8; ++s)
#pragma unroll
    for (int nt = 0; nt < 4; ++nt) {
      short8 bh = *(const short8*)&HbufB[rb + (nt * 8 + s) * 512];
      accB[0][nt] = __builtin_amdgcn_mfma_f32_16x16x32_bf16(w2f[s][0], bh, accB[0][nt], 0, 0, 0);
      accB[1][nt] = __builtin_amdgcn_mfma_f32_16x16x32_bf16(w2f[s][1], bh, accB[1][nt], 0, 0, 0);
    }
  __syncthreads();
#pragma unroll
  for (int u = 0; u < 8; ++u) ePart(u, accB, HbufB);
  __syncthreads();

  // ---- steady state: 5 intervals per it, MFMA⇄VALU fused per step ----
#pragma unroll 1
  for (int it = 0; it < NSTEPS * 4; ++it) {
    const int st = it & 3;

    // k=0: A:P1 (16 MFMA) fused with B:P3 (16 MFMA) + B RK4 tail
    {
      initAcc(accA, b1a);
      floatx4 a3[2];
      a3[0] = floatx4{b3a[0], b3a[1], b3a[2], b3a[3]};
      a3[1] = a3[0];
#pragma unroll
      for (int u = 0; u < 8; ++u) {
        p3Step(u, HbufB, a3);
        p1Step(u, ZbufA, accA);
      }
      rk4Tail(a3, zB, zaccB, ZbufB, st);
    }
    __syncthreads();

    // k=1: B:P1 (16 MFMA) fused with A:E1 (32 tanh)
    {
      initAcc(accB, b1a);
#pragma unroll
      for (int u = 0; u < 8; ++u) {
        p1Step(u, ZbufB, accB);
        ePart(u, accA, HbufA);
      }
    }
    __syncthreads();

    // k=2: A:P2 (64 MFMA) fused with B:E1 (32 tanh)
    {
      initAcc(accA, b2a);
#pragma unroll
      for (int s = 0; s < 8; ++s) {
#pragma unroll
        for (int nt = 0; nt < 4; ++nt) {
          short8 bh = *(const short8*)&HbufA[rb + (nt * 8 + s) * 512];
          accA[0][nt] = __builtin_amdgcn_mfma_f32_16x16x32_bf16(w2f[s][0], bh, accA[0][nt], 0, 0, 0);
          accA[1][nt] = __builtin_amdgcn_mfma_f32_16x16x32_bf16(w2f[s][1], bh, accA[1][nt], 0, 0, 0);
        }
        ePart(s, accB, HbufB);
      }
    }
    __syncthreads();

    // k=3: B:P2 (64 MFMA) fused with A:E2 (32 tanh)
    {
      initAcc(accB, b2a);
#pragma unroll
      for (int s = 0; s < 8; ++s) {
#pragma unroll
        for (int nt = 0; nt < 4; ++nt) {
          short8 bh = *(const short8*)&HbufB[rb + (nt * 8 + s) * 512];
          accB[0][nt] = __builtin_amdgcn_mfma_f32_16x16x32_bf16(w2f[s][0], bh, accB[0][nt], 0, 0, 0);
          accB[1][nt] = __builtin_amdgcn_mfma_f32_16x16x32_bf16(w2f[s][1], bh, accB[1][nt], 0, 0, 0);
        }
        ePart(s, accA, HbufA);
      }
    }
    __syncthreads();

    // k=4: A:P3 (16 MFMA) + A RK4, fused with B:E2 (32 tanh)
    {
      floatx4 a3[2];
      a3[0] = floatx4{b3a[0], b3a[1], b3a[2], b3a[3]};
      a3[1] = a3[0];
#pragma unroll
      for (int u = 0; u < 8; ++u) {
        p3Step(u, HbufA, a3);
        ePart(u, accB, HbufB);
      }
      rk4Tail(a3, zA, zaccA, ZbufA, st);
    }
    __syncthreads();
  }
  // (B's trailing stage-400 P1/P2/E work never runs P3, so zB is final.)

  // ---- final store, both groups ----
#pragma unroll
  for (int j = 0; j < 2; ++j) {
    const int nt = 2 * ntp + j;
    float4 va, vb;
    va.x = zA[j*4+0]; va.y = zA[j*4+1]; va.z = zA[j*4+2]; va.w = zA[j*4+3];
    vb.x = zB[j*4+0]; vb.y = zB[j*4+1]; vb.z = zB[j*4+2]; vb.w = zB[j*4+3];
    *(float4*)&out[(grow + nt * 16 + i15) * 64 + mt3 * 16 + q * 4] = va;
    *(float4*)&out[(grow + 64 + nt * 16 + i15) * 64 + mt3 * 16 + q * 4] = vb;
  }
}

extern "C" void kernel_launch(void* const* d_in, const int* in_sizes, int n_in,
                              void* d_out, int out_size, void* d_ws, size_t ws_size,
                              hipStream_t stream) {
  const float* z0 = (const float*)d_in[0];
  const float* W1 = (const float*)d_in[1];
  const float* b1 = (const float*)d_in[2];
  const float* W2 = (const float*)d_in[3];
  const float* b2 = (const float*)d_in[4];
  const float* W3 = (const float*)d_in[5];
  const float* b3 = (const float*)d_in[6];
  unsigned short* ws = (unsigned short*)d_ws;  // 98304 bf16 = 196608 B

  prep_weights<<<384, 256, 0, stream>>>(W1, W2, W3, ws);
  (void)hipFuncSetAttribute((const void*)cnf_kernel,
                            hipFuncAttributeMaxDynamicSharedMemorySize, 147456);
  cnf_kernel<<<256, 512, 147456, stream>>>(z0, b1, b2, b3, ws, (float*)d_out);
}

// Round 2
// 2642.168 us; speedup vs baseline: 1.0951x; 1.0951x over previous
//
#include <hip/hip_runtime.h>
#include <hip/hip_bf16.h>

#define NSTEPS 100
#define DT (1.0f / 100.0f)
#define TSCALE 2.885390081777927f   // 2*log2(e): folded into W1,W2,b1,b2

typedef __attribute__((ext_vector_type(8))) short short8;   // 8 bf16 (MFMA A/B frag)
typedef __attribute__((ext_vector_type(4))) float floatx4;  // MFMA C/D frag

__device__ __forceinline__ unsigned short f2bf(float f) {
  union { float f; unsigned int u; } v; v.f = f;
  unsigned int u = v.u;
  return (unsigned short)((u + 0x7fffu + ((u >> 16) & 1u)) >> 16);  // RNE
}
__device__ __forceinline__ unsigned int pk2(float a, float b) {
  __hip_bfloat162 h = __float22bfloat162_rn(make_float2(a, b));
  union { __hip_bfloat162 h; unsigned int u; } v; v.h = h;
  return v.u;
}
// tanh with input pre-scaled by 2*log2(e): tanh = 1 - 2/(2^y + 1)
__device__ __forceinline__ float tanh_pre(float y) {
  float e = __builtin_amdgcn_exp2f(y);
  return 1.0f - 2.0f * __builtin_amdgcn_rcpf(e + 1.0f);
}

// Repack W (K x N row-major fp32) into frag-major bf16 (A-frag of W^T).
// W1/W2 are pre-scaled by TSCALE (tanh input scale folded in).
__global__ void prep_weights(const float* __restrict__ W1,
                             const float* __restrict__ W2,
                             const float* __restrict__ W3,
                             unsigned short* __restrict__ ws) {
  int e = blockIdx.x * 256 + threadIdx.x;  // 98304 total
  const float* src; int N, ntile, el, base; float sc;
  if (e < 16384)      { src = W1; N = 256; ntile = 16; base = 0;     el = e;         sc = TSCALE; }
  else if (e < 81920) { src = W2; N = 256; ntile = 16; base = 16384; el = e - 16384; sc = TSCALE; }
  else                { src = W3; N = 64;  ntile = 4;  base = 81920; el = e - 81920; sc = 1.0f; }
  int j = el & 7;
  int l = (el >> 3) & 63;
  int rem = el >> 9;
  int t = rem % ntile;
  int s = rem / ntile;
  int k = s * 32 + ((l >> 4) << 3) + j;
  int n = t * 16 + (l & 15);
  ws[base + el] = f2bf(src[k * N + n] * sc);
}

// Dual-group pipeline with MFMA and tanh streams fused at statement
// granularity. R2 change: ALL weights register-resident (W1 4 frags/wave,
// W2 16 frags/wave, W3 8 frags/wave) -> LDS reads drop 160->96 per
// wave-iter (kernel was LDS-pipe-bound at ~80-95%); LDS 144->80 KiB.
// Bias frags feed the first MFMA of each chain as C (no acc-init movs).
__global__ __launch_bounds__(512, 2)
void cnf_kernel(const float* __restrict__ z0,
                const float* __restrict__ b1,
                const float* __restrict__ b2,
                const float* __restrict__ b3,
                const unsigned short* __restrict__ wsAll,
                float* __restrict__ out) {
  extern __shared__ unsigned short smem[];   // 81920 B
  unsigned short* ZbufA = smem;              //  8192 B (4 nt * 2 s * 512)
  unsigned short* ZbufB = smem + 4096;
  unsigned short* HbufA = smem + 8192;       // 32768 B (4 nt * 8 s * 512)
  unsigned short* HbufB = smem + 24576;

  const int tid  = threadIdx.x;
  const int wave = tid >> 6;
  const int lane = tid & 63;
  const int i15  = lane & 15;
  const int q    = lane >> 4;
  const int grow = blockIdx.x * 128;         // group A rows; B = +64
  const int mt3  = wave & 3;                 // L3 M-tile
  const int ntp  = wave >> 2;                // L3 N-pair

  const unsigned short* wsW1 = wsAll;
  const unsigned short* wsW2 = wsAll + 16384;
  const unsigned short* wsW3 = wsAll + 81920;

  // ---- register-resident weight A-frags ----
  // W1: per wave only its 2 hid-tiles x 2 K-slices = 4 frags (16 VGPR)
  short8 w1f[2][2];
#pragma unroll
  for (int s = 0; s < 2; ++s)
#pragma unroll
    for (int tt = 0; tt < 2; ++tt)
      w1f[s][tt] = *(const short8*)&wsW1[((s * 16 + 2 * wave + tt) * 64 + lane) * 8];
  // W2: 16 frags (64 VGPR)
  short8 w2f[8][2];
#pragma unroll
  for (int s = 0; s < 8; ++s)
#pragma unroll
    for (int tt = 0; tt < 2; ++tt)
      w2f[s][tt] = *(const short8*)&wsW2[((s * 16 + 2 * wave + tt) * 64 + lane) * 8];
  // W3: per wave its M-tile x 8 K-slices = 8 frags (32 VGPR)
  short8 w3f[8];
#pragma unroll
  for (int s = 0; s < 8; ++s)
    w3f[s] = *(const short8*)&wsW3[((s * 4 + mt3) * 64 + lane) * 8];

  // ---- bias C-frags (fp32); b1/b2 pre-scaled by TSCALE ----
  floatx4 b1f[2], b2f[2], b3f;
#pragma unroll
  for (int tt = 0; tt < 2; ++tt) {
    float4 v1 = *(const float4*)&b1[(2 * wave + tt) * 16 + q * 4];
    float4 v2 = *(const float4*)&b2[(2 * wave + tt) * 16 + q * 4];
    b1f[tt] = floatx4{v1.x * TSCALE, v1.y * TSCALE, v1.z * TSCALE, v1.w * TSCALE};
    b2f[tt] = floatx4{v2.x * TSCALE, v2.y * TSCALE, v2.z * TSCALE, v2.w * TSCALE};
  }
  {
    float4 v3 = *(const float4*)&b3[mt3 * 16 + q * 4];
    b3f = floatx4{v3.x, v3.y, v3.z, v3.w};
  }

  // ---- frag-layout index bases ----
  const int rb  = lane * 8;                                   // act read base; tile adds *512
  const int j0  = 4 * (q & 1);
  const int hw0 = (wave * 64 + i15 + 16 * (q >> 1)) * 8 + j0; // +tt*256, +nt*4096
  const int zw0 = ((mt3 >> 1) * 64 + i15 + 16 * (2 * (mt3 & 1) + (q >> 1))) * 8 + j0;  // +nt*1024

  // ---- RK4 state, both groups ----
  float zA[8], zaccA[8], zB[8], zaccB[8];
#pragma unroll
  for (int j = 0; j < 2; ++j) {
    const int nt = 2 * ntp + j;
    float4 va = *(const float4*)&z0[(grow + nt * 16 + i15) * 64 + mt3 * 16 + q * 4];
    float4 vb = *(const float4*)&z0[(grow + 64 + nt * 16 + i15) * 64 + mt3 * 16 + q * 4];
    zA[j*4+0]=va.x; zA[j*4+1]=va.y; zA[j*4+2]=va.z; zA[j*4+3]=va.w;
    zB[j*4+0]=vb.x; zB[j*4+1]=vb.y; zB[j*4+2]=vb.z; zB[j*4+3]=vb.w;
#pragma unroll
    for (int r = 0; r < 4; ++r) { zaccA[j*4+r] = 0.f; zaccB[j*4+r] = 0.f; }
    uint2 pa; pa.x = pk2(va.x, va.y); pa.y = pk2(va.z, va.w);
    uint2 pb; pb.x = pk2(vb.x, vb.y); pb.y = pk2(vb.z, vb.w);
    *(uint2*)&ZbufA[zw0 + nt * 1024] = pa;
    *(uint2*)&ZbufB[zw0 + nt * 1024] = pb;
  }

  const float DT6 = DT / 6.0f, DT3 = DT / 3.0f, DTH = 0.5f * DT;

  floatx4 accA[2][4], accB[2][4];

  // ---- helpers ----
  // one-eighth of an epilogue: 4 tanh + 2 packs + 1 b64 write
  auto ePart = [&](int u, floatx4 (&a)[2][4], unsigned short* H) {
    const int tt = u >> 2, nt = u & 3;
    uint2 p;
    p.x = pk2(tanh_pre(a[tt][nt][0]), tanh_pre(a[tt][nt][1]));
    p.y = pk2(tanh_pre(a[tt][nt][2]), tanh_pre(a[tt][nt][3]));
    *(uint2*)&H[hw0 + tt * 256 + nt * 4096] = p;
  };
  // one step of L1 (pair u: s=u>>2, nt=u&3): 2 MFMAs; s==0 starts from bias-C
  auto p1Step = [&](int u, const unsigned short* Z, floatx4 (&a)[2][4]) {
    const int s = u >> 2, nt = u & 3;
    short8 bz = *(const short8*)&Z[rb + (nt * 2 + s) * 512];
    if (s == 0) {
      a[0][nt] = __builtin_amdgcn_mfma_f32_16x16x32_bf16(w1f[0][0], bz, b1f[0], 0, 0, 0);
      a[1][nt] = __builtin_amdgcn_mfma_f32_16x16x32_bf16(w1f[0][1], bz, b1f[1], 0, 0, 0);
    } else {
      a[0][nt] = __builtin_amdgcn_mfma_f32_16x16x32_bf16(w1f[1][0], bz, a[0][nt], 0, 0, 0);
      a[1][nt] = __builtin_amdgcn_mfma_f32_16x16x32_bf16(w1f[1][1], bz, a[1][nt], 0, 0, 0);
    }
  };
  // one s-step of L3: 2 MFMAs; s==0 starts from bias-C
  auto p3Step = [&](int s, const unsigned short* H, floatx4 (&a3)[2]) {
    short8 b0 = *(const short8*)&H[rb + (ntp * 16 + s) * 512];
    short8 b1_ = *(const short8*)&H[rb + (ntp * 16 + 8 + s) * 512];
    if (s == 0) {
      a3[0] = __builtin_amdgcn_mfma_f32_16x16x32_bf16(w3f[0], b0, b3f, 0, 0, 0);
      a3[1] = __builtin_amdgcn_mfma_f32_16x16x32_bf16(w3f[0], b1_, b3f, 0, 0, 0);
    } else {
      a3[0] = __builtin_amdgcn_mfma_f32_16x16x32_bf16(w3f[s], b0, a3[0], 0, 0, 0);
      a3[1] = __builtin_amdgcn_mfma_f32_16x16x32_bf16(w3f[s], b1_, a3[1], 0, 0, 0);
    }
  };
  auto rk4Tail = [&](floatx4 (&a3)[2], float (&z)[8], float (&zacc)[8],
                     unsigned short* Z, int st) {
    const float wsum  = (st == 0 || st == 3) ? DT6 : DT3;
    const float cst   = (st == 2) ? DT : DTH;
    const bool  last  = (st == 3);
    const bool  first = (st == 0);
#pragma unroll
    for (int j = 0; j < 2; ++j) {
      const int nt = 2 * ntp + j;
      float stg[4];
#pragma unroll
      for (int r = 0; r < 4; ++r) {
        const int i = j * 4 + r;
        float k = a3[j][r];
        float za = first ? z[i] : zacc[i];
        za += wsum * k;
        zacc[i] = za;
        if (last) { z[i] = za; stg[r] = za; }
        else      { stg[r] = z[i] + cst * k; }
      }
      uint2 p; p.x = pk2(stg[0], stg[1]); p.y = pk2(stg[2], stg[3]);
      *(uint2*)&Z[zw0 + nt * 1024] = p;
    }
  };

  // ---- prologue: advance B through P1,E1,P2,E2 of stage 0 (unfused) ----
  __syncthreads();                 // Zbuf init visible
#pragma unroll
  for (int u = 0; u < 8; ++u) p1Step(u, ZbufB, accB);
#pragma unroll
  for (int u = 0; u < 8; ++u) ePart(u, accB, HbufB);
  __syncthreads();
#pragma unroll
  for (int s = 0; s < 8; ++s)
#pragma unroll
    for (int nt = 0; nt < 4; ++nt) {
      short8 bh = *(const short8*)&HbufB[rb + (nt * 8 + s) * 512];
      accB[0][nt] = __builtin_amdgcn_mfma_f32_16x16x32_bf16(w2f[s][0], bh,
                      s == 0 ? b2f[0] : accB[0][nt], 0, 0, 0);
      accB[1][nt] = __builtin_amdgcn_mfma_f32_16x16x32_bf16(w2f[s][1], bh,
                      s == 0 ? b2f[1] : accB[1][nt], 0, 0, 0);
    }
  __syncthreads();
#pragma unroll
  for (int u = 0; u < 8; ++u) ePart(u, accB, HbufB);
  __syncthreads();

  // ---- steady state: 5 intervals per it, MFMA⇄VALU fused per step ----
#pragma unroll 1
  for (int it = 0; it < NSTEPS * 4; ++it) {
    const int st = it & 3;

    // k=0: A:P1 (16 MFMA) fused with B:P3 (16 MFMA) + B RK4 tail
    {
      floatx4 a3[2];
#pragma unroll
      for (int u = 0; u < 8; ++u) {
        p3Step(u, HbufB, a3);
        p1Step(u, ZbufA, accA);
      }
      rk4Tail(a3, zB, zaccB, ZbufB, st);
    }
    __syncthreads();

    // k=1: B:P1 (16 MFMA) fused with A:E1 (32 tanh)
    {
#pragma unroll
      for (int u = 0; u < 8; ++u) {
        p1Step(u, ZbufB, accB);
        ePart(u, accA, HbufA);
      }
    }
    __syncthreads();

    // k=2: A:P2 (64 MFMA) fused with B:E1 (32 tanh)
    {
#pragma unroll
      for (int s = 0; s < 8; ++s) {
#pragma unroll
        for (int nt = 0; nt < 4; ++nt) {
          short8 bh = *(const short8*)&HbufA[rb + (nt * 8 + s) * 512];
          accA[0][nt] = __builtin_amdgcn_mfma_f32_16x16x32_bf16(w2f[s][0], bh,
                          s == 0 ? b2f[0] : accA[0][nt], 0, 0, 0);
          accA[1][nt] = __builtin_amdgcn_mfma_f32_16x16x32_bf16(w2f[s][1], bh,
                          s == 0 ? b2f[1] : accA[1][nt], 0, 0, 0);
        }
        ePart(s, accB, HbufB);
      }
    }
    __syncthreads();

    // k=3: B:P2 (64 MFMA) fused with A:E2 (32 tanh)
    {
#pragma unroll
      for (int s = 0; s < 8; ++s) {
#pragma unroll
        for (int nt = 0; nt < 4; ++nt) {
          short8 bh = *(const short8*)&HbufB[rb + (nt * 8 + s) * 512];
          accB[0][nt] = __builtin_amdgcn_mfma_f32_16x16x32_bf16(w2f[s][0], bh,
                          s == 0 ? b2f[0] : accB[0][nt], 0, 0, 0);
          accB[1][nt] = __builtin_amdgcn_mfma_f32_16x16x32_bf16(w2f[s][1], bh,
                          s == 0 ? b2f[1] : accB[1][nt], 0, 0, 0);
        }
        ePart(s, accA, HbufA);
      }
    }
    __syncthreads();

    // k=4: A:P3 (16 MFMA) + A RK4, fused with B:E2 (32 tanh)
    {
      floatx4 a3[2];
#pragma unroll
      for (int u = 0; u < 8; ++u) {
        p3Step(u, HbufA, a3);
        ePart(u, accB, HbufB);
      }
      rk4Tail(a3, zA, zaccA, ZbufA, st);
    }
    __syncthreads();
  }
  // (B's trailing stage-400 P1/P2/E work never runs P3, so zB is final.)

  // ---- final store, both groups ----
#pragma unroll
  for (int j = 0; j < 2; ++j) {
    const int nt = 2 * ntp + j;
    float4 va, vb;
    va.x = zA[j*4+0]; va.y = zA[j*4+1]; va.z = zA[j*4+2]; va.w = zA[j*4+3];
    vb.x = zB[j*4+0]; vb.y = zB[j*4+1]; vb.z = zB[j*4+2]; vb.w = zB[j*4+3];
    *(float4*)&out[(grow + nt * 16 + i15) * 64 + mt3 * 16 + q * 4] = va;
    *(float4*)&out[(grow + 64 + nt * 16 + i15) * 64 + mt3 * 16 + q * 4] = vb;
  }
}

extern "C" void kernel_launch(void* const* d_in, const int* in_sizes, int n_in,
                              void* d_out, int out_size, void* d_ws, size_t ws_size,
                              hipStream_t stream) {
  const float* z0 = (const float*)d_in[0];
  const float* W1 = (const float*)d_in[1];
  const float* b1 = (const float*)d_in[2];
  const float* W2 = (const float*)d_in[3];
  const float* b2 = (const float*)d_in[4];
  const float* W3 = (const float*)d_in[5];
  const float* b3 = (const float*)d_in[6];
  unsigned short* ws = (unsigned short*)d_ws;  // 98304 bf16 = 196608 B

  prep_weights<<<384, 256, 0, stream>>>(W1, W2, W3, ws);
  (void)hipFuncSetAttribute((const void*)cnf_kernel,
                            hipFuncAttributeMaxDynamicSharedMemorySize, 81920);
  cnf_kernel<<<256, 512, 81920, stream>>>(z0, b1, b2, b3, ws, (float*)d_out);
}